// Round 1
// baseline (158.550 us; speedup 1.0000x reference)
//
#include <hip/hip_runtime.h>
#include <math.h>

#define B_   4
#define C_   128
#define H_   96
#define W_   192
#define HW_  (H_*W_)
#define NPIX (B_*HW_)

static __device__ __forceinline__ float dot4(float4 a, float4 b) {
    return a.x*b.x + a.y*b.y + a.z*b.z + a.w*b.w;
}

// ---------------------------------------------------------------------------
// Phase 1: q = f @ Wq^T + bq ; k = f @ Wk^T + bk
// GEMM M=73728 (pixels), K=128, N=256 (q outputs 0..127, k outputs 128..255).
// Block: 256 threads, tile = 64 pixels x 256 outputs.
// Thread t: og = t>>4 (output group, 16 outputs), pg = t&15 (pixel group, 4 px).
// ---------------------------------------------------------------------------
__global__ __launch_bounds__(256) void proj_kernel(
    const float* __restrict__ f,
    const float* __restrict__ Wq, const float* __restrict__ bq,
    const float* __restrict__ Wk, const float* __restrict__ bk,
    float* __restrict__ qout, float* __restrict__ kout)
{
    __shared__ float sF[16][64];    // [k-chunk][pixel]   4 KB
    __shared__ float sW[16][256];   // [k-chunk][out]    16 KB

    const int t   = threadIdx.x;
    const int p0  = blockIdx.x * 64;          // 64 | HW_, so tile stays in one batch
    const int bb  = p0 / HW_;
    const int sp0 = p0 % HW_;
    const int og  = t >> 4;                   // 0..15
    const int pg  = t & 15;                   // 0..15

    float acc[4][16];
#pragma unroll
    for (int i = 0; i < 4; ++i)
#pragma unroll
        for (int j = 0; j < 16; ++j) acc[i][j] = 0.f;

    const float* wsrc = (t < 128) ? (Wq + (size_t)t * C_)
                                  : (Wk + (size_t)(t - 128) * C_);
    const float* fb   = f + (size_t)bb * C_ * HW_ + sp0;

    for (int kc = 0; kc < C_; kc += 16) {
        __syncthreads();
        // stage f chunk: thread loads channel og, pixels pg*4..+3 (coalesced float4)
        float4 fv4 = *(const float4*)(fb + (size_t)(kc + og) * HW_ + pg * 4);
        *(float4*)&sF[og][pg * 4] = fv4;

        // stage W chunk: thread t owns output row t, reads 16 contiguous floats
        float4 wv0 = *(const float4*)(wsrc + kc + 0);
        float4 wv1 = *(const float4*)(wsrc + kc + 4);
        float4 wv2 = *(const float4*)(wsrc + kc + 8);
        float4 wv3 = *(const float4*)(wsrc + kc + 12);
        float wt[16] = {wv0.x, wv0.y, wv0.z, wv0.w,
                        wv1.x, wv1.y, wv1.z, wv1.w,
                        wv2.x, wv2.y, wv2.z, wv2.w,
                        wv3.x, wv3.y, wv3.z, wv3.w};
#pragma unroll
        for (int kk = 0; kk < 16; ++kk) sW[kk][t] = wt[kk];  // 2-way/bank: free
        __syncthreads();

#pragma unroll
        for (int kk = 0; kk < 16; ++kk) {
            float4 fv = *(const float4*)&sF[kk][pg * 4];
            float4 w0 = *(const float4*)&sW[kk][og * 16 + 0];
            float4 w1 = *(const float4*)&sW[kk][og * 16 + 4];
            float4 w2 = *(const float4*)&sW[kk][og * 16 + 8];
            float4 w3 = *(const float4*)&sW[kk][og * 16 + 12];
            float fa[4]  = {fv.x, fv.y, fv.z, fv.w};
            float wa[16] = {w0.x, w0.y, w0.z, w0.w, w1.x, w1.y, w1.z, w1.w,
                            w2.x, w2.y, w2.z, w2.w, w3.x, w3.y, w3.z, w3.w};
#pragma unroll
            for (int i = 0; i < 4; ++i)
#pragma unroll
                for (int j = 0; j < 16; ++j)
                    acc[i][j] = fmaf(fa[i], wa[j], acc[i][j]);
        }
    }

    // epilogue: og<8 -> q channels, og>=8 -> k channels
    const bool  isq  = (og < 8);
    const int   ch0  = (og * 16) & 127;
    const float* bias = isq ? bq : bk;
    float* dst = isq ? qout : kout;
    float bv[16];
#pragma unroll
    for (int j = 0; j < 16; ++j) bv[j] = bias[ch0 + j];

#pragma unroll
    for (int i = 0; i < 4; ++i) {
        const int p = p0 + pg * 4 + i;
        float* d = dst + (size_t)p * C_ + ch0;
#pragma unroll
        for (int jj = 0; jj < 4; ++jj) {
            float4 o;
            o.x = acc[i][jj*4+0] + bv[jj*4+0];
            o.y = acc[i][jj*4+1] + bv[jj*4+1];
            o.z = acc[i][jj*4+2] + bv[jj*4+2];
            o.w = acc[i][jj*4+3] + bv[jj*4+3];
            *(float4*)(d + jj*4) = o;
        }
    }
}

// ---------------------------------------------------------------------------
// Phase 2: per-pixel 3x3 window attention.
// Zero-padding semantics: OOB neighbor -> score contribution exactly 0
// (participates in softmax), v contribution 0.
// ---------------------------------------------------------------------------
__global__ __launch_bounds__(256) void attn_kernel(
    const float* __restrict__ q, const float* __restrict__ k,
    const float* __restrict__ flow, float* __restrict__ out)
{
    const int p  = blockIdx.x * 256 + threadIdx.x;   // NPIX = 288*256 exactly
    const int bb = p / HW_;
    const int sp = p % HW_;
    const int y  = sp / W_;
    const int x  = sp % W_;

    int   spn[9];
    float msk[9];
#pragma unroll
    for (int n = 0; n < 9; ++n) {
        const int yn = y + n / 3 - 1;
        const int xn = x + n % 3 - 1;
        const bool v = (yn >= 0) && (yn < H_) && (xn >= 0) && (xn < W_);
        msk[n] = v ? 1.f : 0.f;
        spn[n] = v ? (yn * W_ + xn) : sp;   // clamp to own pixel; masked later
    }

    const float* qp  = q + (size_t)p * C_;
    const float* kbb = k + (size_t)bb * HW_ * C_;
    float s[9];
#pragma unroll
    for (int n = 0; n < 9; ++n) s[n] = 0.f;

    for (int jc = 0; jc < 8; ++jc) {        // 16 channels per chunk
        float4 qa0 = ((const float4*)qp)[jc * 4 + 0];
        float4 qa1 = ((const float4*)qp)[jc * 4 + 1];
        float4 qa2 = ((const float4*)qp)[jc * 4 + 2];
        float4 qa3 = ((const float4*)qp)[jc * 4 + 3];
#pragma unroll
        for (int n = 0; n < 9; ++n) {
            const float4* kp = (const float4*)(kbb + (size_t)spn[n] * C_);
            float4 k0 = kp[jc * 4 + 0];
            float4 k1 = kp[jc * 4 + 1];
            float4 k2 = kp[jc * 4 + 2];
            float4 k3 = kp[jc * 4 + 3];
            s[n] += dot4(qa0, k0) + dot4(qa1, k1) + dot4(qa2, k2) + dot4(qa3, k3);
        }
    }

    const float scale = 0.08838834764831845f;  // 1/sqrt(128)
    float m = -1e30f;
#pragma unroll
    for (int n = 0; n < 9; ++n) { s[n] = s[n] * scale * msk[n]; m = fmaxf(m, s[n]); }
    float e[9], sum = 0.f;
#pragma unroll
    for (int n = 0; n < 9; ++n) { e[n] = __expf(s[n] - m); sum += e[n]; }
    const float inv = 1.f / sum;

    const float* f0 = flow + (size_t)bb * 2 * HW_;
    float o0 = 0.f, o1 = 0.f;
#pragma unroll
    for (int n = 0; n < 9; ++n) {
        const float pr = e[n] * inv * msk[n];
        o0 += pr * f0[spn[n]];
        o1 += pr * f0[HW_ + spn[n]];
    }
    out[(size_t)bb * 2 * HW_ + sp]       = o0;
    out[(size_t)bb * 2 * HW_ + HW_ + sp] = o1;
}

extern "C" void kernel_launch(void* const* d_in, const int* in_sizes, int n_in,
                              void* d_out, int out_size, void* d_ws, size_t ws_size,
                              hipStream_t stream) {
    const float* f   = (const float*)d_in[0];
    const float* flw = (const float*)d_in[1];
    const float* Wq  = (const float*)d_in[2];
    const float* bq  = (const float*)d_in[3];
    const float* Wk  = (const float*)d_in[4];
    const float* bk  = (const float*)d_in[5];
    float* out = (float*)d_out;

    float* qws = (float*)d_ws;                       // [NPIX][C]  37.7 MB
    float* kws = qws + (size_t)NPIX * C_;            // [NPIX][C]  37.7 MB

    proj_kernel<<<NPIX / 64, 256, 0, stream>>>(f, Wq, bq, Wk, bk, qws, kws);
    attn_kernel<<<NPIX / 256, 256, 0, stream>>>(qws, kws, flw, out);
}

// Round 2
// 83.566 us; speedup vs baseline: 1.8973x; 1.8973x over previous
//
#include <hip/hip_runtime.h>
#include <math.h>

#define B_   4
#define C_   128
#define H_   96
#define W_   192
#define HW_  (H_*W_)
#define NPIX (B_*HW_)

typedef __attribute__((ext_vector_type(8))) short bf16x8;
typedef __attribute__((ext_vector_type(4))) float f32x4;

__device__ __forceinline__ unsigned short f2bf(float f) {
    unsigned u = __float_as_uint(f);
    u = (u + 0x7FFFu + ((u >> 16) & 1u)) >> 16;   // RNE
    return (unsigned short)u;
}
__device__ __forceinline__ float bflo(unsigned u) { return __uint_as_float(u << 16); }
__device__ __forceinline__ float bfhi(unsigned u) { return __uint_as_float(u & 0xFFFF0000u); }

// ---------------------------------------------------------------------------
// Pack Wq||Wk (256 rows x 128 k, fp32) into bf16 MFMA A-fragment order.
// Apack[((rtg*4 + kstep)*64 + lane)*8 + j] = W2[rtg*16 + (lane&15)][kstep*32 + (lane>>4)*8 + j]
// ---------------------------------------------------------------------------
__global__ __launch_bounds__(256) void pack_w_kernel(
    const float* __restrict__ Wq, const float* __restrict__ Wk,
    short* __restrict__ Apack)
{
    const int tid  = blockIdx.x * 256 + threadIdx.x;   // 4096 threads
    const int lane = tid & 63;
    const int kst  = (tid >> 6) & 3;
    const int rtg  = tid >> 8;
    const int row  = rtg * 16 + (lane & 15);
    const int kb   = kst * 32 + (lane >> 4) * 8;
    const float* src = (row < 128) ? (Wq + (size_t)row * C_ + kb)
                                   : (Wk + (size_t)(row - 128) * C_ + kb);
    bf16x8 v;
#pragma unroll
    for (int j = 0; j < 8; ++j) v[j] = (short)f2bf(src[j]);
    *(bf16x8*)(Apack + (size_t)tid * 8) = v;
}

// ---------------------------------------------------------------------------
// proj: D[out=256][px] = W2 @ f  per batch, bf16 MFMA, fp32 accum.
// Block: 256 thr = 4 waves (wm x wn = 2x2). Block tile: 128 out-ch x 128 px.
// blockIdx: mb = bit0 (q vs k half), pblk = rest. No LDS, no barriers.
// A-frags from packed bf16 (coalesced 16B/lane); B-frags direct from planar
// fp32 f (8 coalesced dword loads each), converted in-register.
// Output planar bf16: q[b][c][hw], k[b][c][hw].
// ---------------------------------------------------------------------------
__global__ __launch_bounds__(256) void proj_kernel(
    const float* __restrict__ f, const short* __restrict__ Apack,
    const float* __restrict__ bq, const float* __restrict__ bk,
    unsigned short* __restrict__ qws, unsigned short* __restrict__ kws)
{
    const int t    = threadIdx.x;
    const int lane = t & 63;
    const int wv   = t >> 6;
    const int wm   = wv >> 1, wn = wv & 1;
    const int mb   = blockIdx.x & 1;
    const int pblk = blockIdx.x >> 1;
    const int gpx0 = pblk * 128;                  // 128 | HW_, one batch per block
    const int b    = gpx0 / HW_;
    const int sp0  = gpx0 % HW_;
    const int lcol = lane & 15, lgrp = lane >> 4;
    const int px0  = sp0 + wn * 64 + lcol;        // + cb*16 added per fragment
    const float* fb = f + (size_t)b * C_ * HW_;

    f32x4 acc[4][4];
#pragma unroll
    for (int i = 0; i < 4; ++i)
#pragma unroll
        for (int j = 0; j < 4; ++j) acc[i][j] = (f32x4){0.f, 0.f, 0.f, 0.f};

#pragma unroll
    for (int ks = 0; ks < 4; ++ks) {
        bf16x8 afr[4];
#pragma unroll
        for (int rb = 0; rb < 4; ++rb) {
            const int rtg = mb * 8 + wm * 4 + rb;
            afr[rb] = *(const bf16x8*)(Apack + ((size_t)(rtg * 4 + ks) * 64 + lane) * 8);
        }
        bf16x8 bfr[4];
#pragma unroll
        for (int cb = 0; cb < 4; ++cb) {
            const float* fp = fb + (size_t)(ks * 32 + lgrp * 8) * HW_ + (px0 + cb * 16);
            bf16x8 v;
#pragma unroll
            for (int j = 0; j < 8; ++j) v[j] = (short)f2bf(fp[(size_t)j * HW_]);
            bfr[cb] = v;
        }
#pragma unroll
        for (int rb = 0; rb < 4; ++rb)
#pragma unroll
            for (int cb = 0; cb < 4; ++cb)
                acc[rb][cb] = __builtin_amdgcn_mfma_f32_16x16x32_bf16(
                    afr[rb], bfr[cb], acc[rb][cb], 0, 0, 0);
    }

    // Epilogue: C/D map col=lane&15 (px), row=(lane>>4)*4+r (out-ch).
    const float* bias = mb ? bk : bq;
    unsigned short* dst = (mb ? kws : qws) + (size_t)b * C_ * HW_;
#pragma unroll
    for (int rb = 0; rb < 4; ++rb) {
#pragma unroll
        for (int r = 0; r < 4; ++r) {
            const int ch = wm * 64 + rb * 16 + lgrp * 4 + r;
            const float bv = bias[ch];
            unsigned short* dp = dst + (size_t)ch * HW_ + px0;
#pragma unroll
            for (int cb = 0; cb < 4; ++cb)
                dp[cb * 16] = f2bf(acc[rb][cb][r] + bv);
        }
    }
}

// ---------------------------------------------------------------------------
// attn: thread = (pixel-pair, 1/8 channel slice). Planar bf16 q/k.
// Per channel: 1 q dword (2 px) + 3 k dwords per dy (cols x-1..x+2).
// 8-way shfl_xor butterfly sums channel partials; lanes cc=0,1 do the
// flow-weighted output for v=0,1.
// ---------------------------------------------------------------------------
__global__ __launch_bounds__(256) void attn_kernel(
    const unsigned short* __restrict__ qws, const unsigned short* __restrict__ kws,
    const float* __restrict__ flow, float* __restrict__ out)
{
    const int t  = threadIdx.x;
    const int cc = t & 7;
    const int P  = blockIdx.x * 32 + (t >> 3);
    const int px0 = 2 * P;
    const int b  = px0 / HW_;
    const int sp = px0 % HW_;
    const int y  = sp / W_;
    const int x  = sp % W_;          // even; pair = (x, x+1), same row

    const unsigned short* qp = qws + (size_t)b * C_ * HW_ + sp;
    const unsigned short* kp = kws + (size_t)b * C_ * HW_;
    const int m0 = x >> 1;
    const int mL = (m0 > 0) ? m0 - 1 : 0;             // clamped; masked later
    const int mR = (m0 < W_ / 2 - 1) ? m0 + 1 : m0;

    int yr[3];
#pragma unroll
    for (int dy = 0; dy < 3; ++dy) {
        int yy = y + dy - 1;
        yr[dy] = yy < 0 ? 0 : (yy >= H_ ? H_ - 1 : yy);   // clamped; masked later
    }

    float s0[9], s1[9];
#pragma unroll
    for (int n = 0; n < 9; ++n) { s0[n] = 0.f; s1[n] = 0.f; }

    const int cbeg = cc * 16;
    for (int ci = 0; ci < 16; ++ci) {
        const int c = cbeg + ci;
        const unsigned qd = *(const unsigned*)(qp + (size_t)c * HW_);
        const float q0 = bflo(qd), q1 = bfhi(qd);
        const unsigned* kpl = (const unsigned*)(kp + (size_t)c * HW_);
#pragma unroll
        for (int dy = 0; dy < 3; ++dy) {
            const unsigned* kr = kpl + yr[dy] * (W_ / 2);
            const unsigned dl = kr[mL], dm = kr[m0], dr = kr[mR];
            const float km1 = bfhi(dl), k0 = bflo(dm), k1 = bfhi(dm), k2 = bflo(dr);
            s0[dy*3+0] += q0 * km1; s0[dy*3+1] += q0 * k0; s0[dy*3+2] += q0 * k1;
            s1[dy*3+0] += q1 * k0;  s1[dy*3+1] += q1 * k1; s1[dy*3+2] += q1 * k2;
        }
    }

#pragma unroll
    for (int d = 1; d < 8; d <<= 1) {
#pragma unroll
        for (int n = 0; n < 9; ++n) {
            s0[n] += __shfl_xor(s0[n], d, 64);
            s1[n] += __shfl_xor(s1[n], d, 64);
        }
    }

    // masks: OOB window element contributes exact 0 score (participates in
    // softmax) and 0 flow value — matches zero-padded reference.
    float mk0[9], mk1[9];
#pragma unroll
    for (int n = 0; n < 9; ++n) {
        const int dy = n / 3 - 1, dx = n % 3 - 1;
        const bool rowok = (y + dy >= 0) && (y + dy < H_);
        mk0[n] = (rowok && (x + dx >= 0) && (x + dx < W_)) ? 1.f : 0.f;
        mk1[n] = (rowok && (x + 1 + dx < W_)) ? 1.f : 0.f;
    }
    const float scale = 0.08838834764831845f;   // 1/sqrt(128)
    float mm0 = -1e30f, mm1 = -1e30f;
#pragma unroll
    for (int n = 0; n < 9; ++n) {
        s0[n] = s0[n] * scale * mk0[n];  mm0 = fmaxf(mm0, s0[n]);
        s1[n] = s1[n] * scale * mk1[n];  mm1 = fmaxf(mm1, s1[n]);
    }
    float e0[9], e1[9], sum0 = 0.f, sum1 = 0.f;
#pragma unroll
    for (int n = 0; n < 9; ++n) {
        e0[n] = __expf(s0[n] - mm0); sum0 += e0[n];
        e1[n] = __expf(s1[n] - mm1); sum1 += e1[n];
    }
    const float inv0 = 1.f / sum0, inv1 = 1.f / sum1;

    if (cc < 2) {
        const int v = cc;
        const float* fl = flow + ((size_t)b * 2 + v) * HW_;
        const int xm1 = (x > 0) ? x - 1 : 0;
        const int xp2 = (x + 2 < W_) ? x + 2 : x;
        float o0 = 0.f, o1 = 0.f;
#pragma unroll
        for (int dy = 0; dy < 3; ++dy) {
            const float* fr = fl + yr[dy] * W_;
            const float fm1 = fr[xm1], f0v = fr[x], f1v = fr[x + 1], f2v = fr[xp2];
            o0 += e0[dy*3+0]*mk0[dy*3+0]*fm1 + e0[dy*3+1]*mk0[dy*3+1]*f0v + e0[dy*3+2]*mk0[dy*3+2]*f1v;
            o1 += e1[dy*3+0]*mk1[dy*3+0]*f0v + e1[dy*3+1]*mk1[dy*3+1]*f1v + e1[dy*3+2]*mk1[dy*3+2]*f2v;
        }
        float2 o = make_float2(o0 * inv0, o1 * inv1);
        *(float2*)(out + ((size_t)b * 2 + v) * HW_ + sp) = o;
    }
}

extern "C" void kernel_launch(void* const* d_in, const int* in_sizes, int n_in,
                              void* d_out, int out_size, void* d_ws, size_t ws_size,
                              hipStream_t stream) {
    const float* f   = (const float*)d_in[0];
    const float* flw = (const float*)d_in[1];
    const float* Wq  = (const float*)d_in[2];
    const float* bq  = (const float*)d_in[3];
    const float* Wk  = (const float*)d_in[4];
    const float* bk  = (const float*)d_in[5];
    float* out = (float*)d_out;

    unsigned short* qws = (unsigned short*)d_ws;          // [B][C][HW] bf16
    unsigned short* kws = qws + (size_t)NPIX * C_;        // [B][C][HW] bf16
    short* Apack = (short*)(kws + (size_t)NPIX * C_);     // 64 KB packed weights

    pack_w_kernel<<<16, 256, 0, stream>>>(Wq, Wk, Apack);
    proj_kernel<<<(NPIX / 128) * 2, 256, 0, stream>>>(f, Apack, bq, bk, qws, kws);
    attn_kernel<<<NPIX / 64, 256, 0, stream>>>(qws, kws, flw, out);
}

// Round 3
// 67.387 us; speedup vs baseline: 2.3528x; 1.2401x over previous
//
#include <hip/hip_runtime.h>
#include <math.h>

#define B_   4
#define C_   128
#define H_   96
#define W_   192
#define HW_  (H_*W_)
#define NPIX (B_*HW_)

typedef __attribute__((ext_vector_type(8))) short bf16x8;
typedef __attribute__((ext_vector_type(4))) float f32x4;

__device__ __forceinline__ unsigned short f2bf(float f) {
    unsigned u = __float_as_uint(f);
    u = (u + 0x7FFFu + ((u >> 16) & 1u)) >> 16;   // RNE
    return (unsigned short)u;
}
__device__ __forceinline__ float bflo(unsigned u) { return __uint_as_float(u << 16); }
__device__ __forceinline__ float bfhi(unsigned u) { return __uint_as_float(u & 0xFFFF0000u); }

// ---------------------------------------------------------------------------
// Pack Wq||Wk (256 rows x 128 k, fp32) into bf16 MFMA A-fragment order.
// Apack[((rtg*4 + ks)*64 + lane)*8 + j] = W2[rtg*16 + (lane&15)][ks*32 + (lane>>4)*8 + j]
// ---------------------------------------------------------------------------
__global__ __launch_bounds__(256) void pack_w_kernel(
    const float* __restrict__ Wq, const float* __restrict__ Wk,
    short* __restrict__ Apack)
{
    const int tid  = blockIdx.x * 256 + threadIdx.x;   // 4096 threads
    const int lane = tid & 63;
    const int kst  = (tid >> 6) & 3;
    const int rtg  = tid >> 8;
    const int row  = rtg * 16 + (lane & 15);
    const int kb   = kst * 32 + (lane >> 4) * 8;
    const float* src = (row < 128) ? (Wq + (size_t)row * C_ + kb)
                                   : (Wk + (size_t)(row - 128) * C_ + kb);
    bf16x8 v;
#pragma unroll
    for (int j = 0; j < 8; ++j) v[j] = (short)f2bf(src[j]);
    *(bf16x8*)(Apack + (size_t)tid * 8) = v;
}

// ---------------------------------------------------------------------------
// proj: q = Wq f + bq, k = Wk f + bk for a 64-px tile, ALL 256 out-ch in one
// block (f read once, converted to bf16 once into LDS).
// Block: 256 thr = 4 waves; wave wv owns out-ch [wv*64, wv*64+64) of q||k.
// LDS: f tile [64 px][128 ch] bf16, 16 KB, 16B-chunk XOR swizzle (chunk ^= px&7)
// -> conflict-free ds_read_b128 / ds_write_b128.
// Output NHWC bf16: q[b][hw][c], k[b][hw][c].
// ---------------------------------------------------------------------------
__global__ __launch_bounds__(256) void proj_kernel(
    const float* __restrict__ f, const short* __restrict__ Apack,
    const float* __restrict__ bq, const float* __restrict__ bk,
    unsigned short* __restrict__ qws, unsigned short* __restrict__ kws)
{
    __shared__ unsigned short sF[64 * 128];   // [px][ch] swizzled, 16 KB

    const int t    = threadIdx.x;
    const int lane = t & 63;
    const int wv   = t >> 6;
    const int gpx0 = blockIdx.x * 64;          // 64 | HW_ -> tile in one batch
    const int b    = gpx0 / HW_;
    const int sp0  = gpx0 % HW_;
    const float* fb = f + (size_t)b * C_ * HW_ + sp0;

    // ---- stage f tile -> bf16 LDS (each thread: 1 px, 4 ch-octets) ----
    {
        const int px = lane;
        const int o0 = wv * 4;
#pragma unroll
        for (int rep = 0; rep < 4; ++rep) {
            const int oct = o0 + rep;          // ch octet 0..15
            bf16x8 v;
#pragma unroll
            for (int j = 0; j < 8; ++j)
                v[j] = (short)f2bf(fb[(size_t)(oct * 8 + j) * HW_ + px]);
            const int chunk = oct ^ (px & 7);
            *(bf16x8*)(sF + px * 128 + chunk * 8) = v;
        }
    }
    __syncthreads();

    const int lcol = lane & 15, lgrp = lane >> 4;

    f32x4 acc[4][4];
#pragma unroll
    for (int i = 0; i < 4; ++i)
#pragma unroll
        for (int j = 0; j < 4; ++j) acc[i][j] = (f32x4){0.f, 0.f, 0.f, 0.f};

#pragma unroll
    for (int ks = 0; ks < 4; ++ks) {
        bf16x8 afr[4];
#pragma unroll
        for (int rb = 0; rb < 4; ++rb)
            afr[rb] = *(const bf16x8*)(Apack +
                ((size_t)((wv * 4 + rb) * 4 + ks) * 64 + lane) * 8);
        bf16x8 bfr[4];
#pragma unroll
        for (int cb = 0; cb < 4; ++cb) {
            const int px = cb * 16 + lcol;
            const int chunk = (ks * 4 + lgrp) ^ (px & 7);
            bfr[cb] = *(const bf16x8*)(sF + px * 128 + chunk * 8);
        }
#pragma unroll
        for (int rb = 0; rb < 4; ++rb)
#pragma unroll
            for (int cb = 0; cb < 4; ++cb)
                acc[rb][cb] = __builtin_amdgcn_mfma_f32_16x16x32_bf16(
                    afr[rb], bfr[cb], acc[rb][cb], 0, 0, 0);
    }

    // ---- epilogue: NHWC bf16 (C/D map: col=lane&15 -> px, row=lgrp*4+r -> ch)
    const float* bias = (wv < 2) ? bq : bk;
    unsigned short* dst = ((wv < 2) ? qws : kws) + (size_t)b * HW_ * C_;
    const int chbase = (wv & 1) * 64 + lgrp * 4;
#pragma unroll
    for (int rb = 0; rb < 4; ++rb) {
        const int ch0 = chbase + rb * 16;
        const float b0 = bias[ch0], b1 = bias[ch0 + 1],
                    b2 = bias[ch0 + 2], b3 = bias[ch0 + 3];
#pragma unroll
        for (int cb = 0; cb < 4; ++cb) {
            const int sp = sp0 + cb * 16 + lcol;
            unsigned short* dp = dst + (size_t)sp * C_ + ch0;
            uint2 o;
            o.x = (unsigned)f2bf(acc[rb][cb][0] + b0)
                | ((unsigned)f2bf(acc[rb][cb][1] + b1) << 16);
            o.y = (unsigned)f2bf(acc[rb][cb][2] + b2)
                | ((unsigned)f2bf(acc[rb][cb][3] + b3) << 16);
            *(uint2*)dp = o;
        }
    }
}

// ---------------------------------------------------------------------------
// attn: thread = one pixel. NHWC q/k -> q is 256 B contiguous, each neighbor
// k-row is 256 B contiguous. 8x16 px tiles (576 blocks) keep the 3x3 halo
// reuse intra-CU (L1/L2). Full per-thread softmax, no cross-lane ops.
// ---------------------------------------------------------------------------
__global__ __launch_bounds__(128) void attn_kernel(
    const unsigned short* __restrict__ qws, const unsigned short* __restrict__ kws,
    const float* __restrict__ flow, float* __restrict__ out)
{
    const int t   = threadIdx.x;               // 128
    const int blk = blockIdx.x;                // 576
    const int xt  = blk % (W_ / 16);           // 12
    const int yt  = (blk / (W_ / 16)) % (H_ / 8);   // 12
    const int b   = blk / ((W_ / 16) * (H_ / 8));   // 4
    const int x   = xt * 16 + (t & 15);
    const int y   = yt * 8 + (t >> 4);
    const int sp  = y * W_ + x;

    int   spn[9];
    float msk[9];
#pragma unroll
    for (int n = 0; n < 9; ++n) {
        const int yn = y + n / 3 - 1;
        const int xn = x + n % 3 - 1;
        const bool v = (yn >= 0) && (yn < H_) && (xn >= 0) && (xn < W_);
        msk[n] = v ? 1.f : 0.f;
        spn[n] = v ? (yn * W_ + xn) : sp;      // clamped; masked later
    }

    const uint4* qv = (const uint4*)(qws + ((size_t)b * HW_ + sp) * C_);
    const unsigned short* kb = kws + (size_t)b * HW_ * C_;

    float s[9];
#pragma unroll
    for (int n = 0; n < 9; ++n) s[n] = 0.f;

#pragma unroll
    for (int chunk = 0; chunk < 4; ++chunk) {   // 32 ch per chunk
        uint4 qd[4];
#pragma unroll
        for (int i = 0; i < 4; ++i) qd[i] = qv[chunk * 4 + i];
        float qf[32];
#pragma unroll
        for (int i = 0; i < 4; ++i) {
            qf[i * 8 + 0] = bflo(qd[i].x); qf[i * 8 + 1] = bfhi(qd[i].x);
            qf[i * 8 + 2] = bflo(qd[i].y); qf[i * 8 + 3] = bfhi(qd[i].y);
            qf[i * 8 + 4] = bflo(qd[i].z); qf[i * 8 + 5] = bfhi(qd[i].z);
            qf[i * 8 + 6] = bflo(qd[i].w); qf[i * 8 + 7] = bfhi(qd[i].w);
        }
#pragma unroll
        for (int n = 0; n < 9; ++n) {
            const uint4* kv = (const uint4*)(kb + (size_t)spn[n] * C_) + chunk * 4;
            float acc = 0.f;
#pragma unroll
            for (int i = 0; i < 4; ++i) {
                const uint4 kd = kv[i];
                acc += bflo(kd.x) * qf[i * 8 + 0] + bfhi(kd.x) * qf[i * 8 + 1]
                     + bflo(kd.y) * qf[i * 8 + 2] + bfhi(kd.y) * qf[i * 8 + 3]
                     + bflo(kd.z) * qf[i * 8 + 4] + bfhi(kd.z) * qf[i * 8 + 5]
                     + bflo(kd.w) * qf[i * 8 + 6] + bfhi(kd.w) * qf[i * 8 + 7];
            }
            s[n] += acc;
        }
    }

    const float scale = 0.08838834764831845f;   // 1/sqrt(128)
    float m = -1e30f;
#pragma unroll
    for (int n = 0; n < 9; ++n) { s[n] = s[n] * scale * msk[n]; m = fmaxf(m, s[n]); }
    float e[9], sum = 0.f;
#pragma unroll
    for (int n = 0; n < 9; ++n) { e[n] = __expf(s[n] - m); sum += e[n]; }
    const float inv = 1.f / sum;

    const float* f0 = flow + (size_t)b * 2 * HW_;
    float o0 = 0.f, o1 = 0.f;
#pragma unroll
    for (int n = 0; n < 9; ++n) {
        const float pr = e[n] * inv * msk[n];
        o0 += pr * f0[spn[n]];
        o1 += pr * f0[HW_ + spn[n]];
    }
    out[(size_t)b * 2 * HW_ + sp]       = o0;
    out[(size_t)b * 2 * HW_ + HW_ + sp] = o1;
}

extern "C" void kernel_launch(void* const* d_in, const int* in_sizes, int n_in,
                              void* d_out, int out_size, void* d_ws, size_t ws_size,
                              hipStream_t stream) {
    const float* f   = (const float*)d_in[0];
    const float* flw = (const float*)d_in[1];
    const float* Wq  = (const float*)d_in[2];
    const float* bq  = (const float*)d_in[3];
    const float* Wk  = (const float*)d_in[4];
    const float* bk  = (const float*)d_in[5];
    float* out = (float*)d_out;

    unsigned short* qws = (unsigned short*)d_ws;          // [B][HW][C] bf16
    unsigned short* kws = qws + (size_t)NPIX * C_;        // [B][HW][C] bf16
    short* Apack = (short*)(kws + (size_t)NPIX * C_);     // 64 KB packed weights

    pack_w_kernel<<<16, 256, 0, stream>>>(Wq, Wk, Apack);
    proj_kernel<<<NPIX / 64, 256, 0, stream>>>(f, Apack, bq, bk, qws, kws);
    attn_kernel<<<NPIX / 128, 128, 0, stream>>>(qws, kws, flw, out);
}

// Round 4
// 53.050 us; speedup vs baseline: 2.9887x; 1.2703x over previous
//
#include <hip/hip_runtime.h>
#include <math.h>

#define B_   4
#define C_   128
#define H_   96
#define W_   192
#define HW_  (H_*W_)
#define NPIX (B_*HW_)

#define TH 8
#define TW 16
#define HX 18          // TW+2
#define HPX 180        // (TH+2)*HX

typedef __attribute__((ext_vector_type(8))) short bf16x8;
typedef __attribute__((ext_vector_type(4))) float f32x4;

__device__ __forceinline__ unsigned short f2bf(float f) {
    unsigned u = __float_as_uint(f);
    u = (u + 0x7FFFu + ((u >> 16) & 1u)) >> 16;   // RNE
    return (unsigned short)u;
}
__device__ __forceinline__ float bflo(unsigned u) { return __uint_as_float(u << 16); }
__device__ __forceinline__ float bfhi(unsigned u) { return __uint_as_float(u & 0xFFFF0000u); }

// ---------------------------------------------------------------------------
// Mc[bch][ach] = sum_c Wk[c][bch] * Wq[c][ach]   (fp32)
// block = one bch row (Wk reads are lane-uniform broadcasts), thread = ach.
// ---------------------------------------------------------------------------
__global__ __launch_bounds__(128) void mc_kernel(
    const float* __restrict__ Wq, const float* __restrict__ Wk,
    float* __restrict__ Mc)
{
    const int bch = blockIdx.x;     // 128
    const int ach = threadIdx.x;    // 128
    float a0 = 0.f, a1 = 0.f, a2 = 0.f, a3 = 0.f;
    for (int c = 0; c < C_; c += 4) {
        a0 = fmaf(Wk[(c + 0) * C_ + bch], Wq[(c + 0) * C_ + ach], a0);
        a1 = fmaf(Wk[(c + 1) * C_ + bch], Wq[(c + 1) * C_ + ach], a1);
        a2 = fmaf(Wk[(c + 2) * C_ + bch], Wq[(c + 2) * C_ + ach], a2);
        a3 = fmaf(Wk[(c + 3) * C_ + bch], Wq[(c + 3) * C_ + ach], a3);
    }
    Mc[bch * C_ + ach] = (a0 + a1) + (a2 + a3);
}

// ---------------------------------------------------------------------------
// blocks 0..7: pack Mc (128x128 fp32) into bf16 MFMA A-fragment order:
//   Apack[((rb*4+ks)*64+lane)*8+j] = Mc[rb*16+(lane&15)][ks*32+(lane>>4)*8+j]
// block 8: u2 = Wk^T bq, v2 = Wq^T bk, c0 = bq.bk
// ---------------------------------------------------------------------------
__global__ __launch_bounds__(256) void pack_kernel(
    const float* __restrict__ Mc,
    const float* __restrict__ Wq, const float* __restrict__ Wk,
    const float* __restrict__ bq, const float* __restrict__ bk,
    short* __restrict__ Apack, float* __restrict__ u2,
    float* __restrict__ v2, float* __restrict__ c0)
{
    if (blockIdx.x < 8) {
        const int tid  = blockIdx.x * 256 + threadIdx.x;   // 0..2047
        const int lane = tid & 63;
        const int ks   = (tid >> 6) & 3;
        const int rb   = tid >> 8;
        const int row  = rb * 16 + (lane & 15);
        const int kb   = ks * 32 + (lane >> 4) * 8;
        const float* src = Mc + row * C_ + kb;
        bf16x8 v;
#pragma unroll
        for (int j = 0; j < 8; ++j) v[j] = (short)f2bf(src[j]);
        *(bf16x8*)(Apack + (size_t)tid * 8) = v;
    } else {
        const int t = threadIdx.x;
        if (t < 128) {
            float a = 0.f;
            for (int c = 0; c < C_; ++c) a = fmaf(Wk[c * C_ + t], bq[c], a);
            u2[t] = a;
        } else {
            const int i = t - 128;
            float a = 0.f;
            for (int c = 0; c < C_; ++c) a = fmaf(Wq[c * C_ + i], bk[c], a);
            v2[i] = a;
        }
        if (t == 0) {
            float a = 0.f;
            for (int c = 0; c < C_; ++c) a = fmaf(bq[c], bk[c], a);
            c0[0] = a;
        }
    }
}

// ---------------------------------------------------------------------------
// Fused: stage f halo (10x18 px, bf16, swizzled) -> r = Mc f + u2 via MFMA
// (acc stays fp32 in regs) -> fragment-domain window dots vs LDS f ->
// butterfly over lane-groups -> per-lane softmax + flow PV -> out.
// Block = 8x16 px tile, 128 thr (2 waves, each 4 rows x 16 cols).
// Grid 576 with XCD-band swizzle (8 bands of 72 contiguous tiles).
// ---------------------------------------------------------------------------
__global__ __launch_bounds__(128) void fused_kernel(
    const float* __restrict__ f, const short* __restrict__ Apack,
    const float* __restrict__ u2v, const float* __restrict__ v2v,
    const float* __restrict__ c0p, const float* __restrict__ flow,
    float* __restrict__ out)
{
    __shared__ unsigned short sH[HPX * 128];   // 45 KB

    const int t    = threadIdx.x;
    const int lane = t & 63;
    const int w    = t >> 6;
    const int lgrp = lane >> 4, lcol = lane & 15;

    const int wg  = blockIdx.x;                   // 576 = 8*72
    const int idx = (wg & 7) * 72 + (wg >> 3);    // XCD-band swizzle (bijective)
    const int b   = idx / 144;
    const int rem = idx - b * 144;
    const int ty  = rem / 12, tx = rem - ty * 12;
    const int y0  = ty * TH, x0 = tx * TW;
    const float* fb = f + (size_t)b * C_ * HW_;

    // ---- stage halo: px t (+128), all 128 ch, bf16, chunk ^= px&15 ----
#pragma unroll
    for (int rep = 0; rep < 2; ++rep) {
        const int px = t + rep * 128;
        if (px < HPX) {
            const int hy = px / HX;
            const int hx = px - hy * HX;
            const int gy = y0 + hy - 1, gx = x0 + hx - 1;
            unsigned short* dst = sH + px * 128;
            if ((gy >= 0) && (gy < H_) && (gx >= 0) && (gx < W_)) {
                const float* src = fb + gy * W_ + gx;
#pragma unroll
                for (int c8 = 0; c8 < 16; ++c8) {
                    bf16x8 v;
#pragma unroll
                    for (int j = 0; j < 8; ++j)
                        v[j] = (short)f2bf(src[(size_t)(c8 * 8 + j) * HW_]);
                    *(bf16x8*)(dst + ((c8 ^ (px & 15)) * 8)) = v;
                }
            } else {
                const bf16x8 z = {0, 0, 0, 0, 0, 0, 0, 0};
#pragma unroll
                for (int c8 = 0; c8 < 16; ++c8)
                    *(bf16x8*)(dst + ((c8 ^ (px & 15)) * 8)) = z;
            }
        }
    }
    __syncthreads();

    // ---- r-GEMM: wave w -> rows w*4..w*4+3, 16 cols, 128 out-ch ----
    f32x4 acc[8][4];
#pragma unroll
    for (int rb = 0; rb < 8; ++rb)
#pragma unroll
        for (int cb = 0; cb < 4; ++cb) acc[rb][cb] = (f32x4){0.f, 0.f, 0.f, 0.f};

#pragma unroll
    for (int ks = 0; ks < 4; ++ks) {
        bf16x8 afr[8];
#pragma unroll
        for (int rb = 0; rb < 8; ++rb)
            afr[rb] = *(const bf16x8*)(Apack + ((size_t)((rb * 4 + ks) * 64 + lane)) * 8);
        bf16x8 bfr[4];
#pragma unroll
        for (int cb = 0; cb < 4; ++cb) {
            const int px = (w * 4 + cb + 1) * HX + (lcol + 1);
            bfr[cb] = *(const bf16x8*)(sH + px * 128 + (((ks * 4 + lgrp) ^ (px & 15)) * 8));
        }
#pragma unroll
        for (int rb = 0; rb < 8; ++rb)
#pragma unroll
            for (int cb = 0; cb < 4; ++cb)
                acc[rb][cb] = __builtin_amdgcn_mfma_f32_16x16x32_bf16(
                    afr[rb], bfr[cb], acc[rb][cb], 0, 0, 0);
    }
    // + u2 bias (per out-ch; lane's ch = rb*16 + lgrp*4 + i)
#pragma unroll
    for (int rb = 0; rb < 8; ++rb) {
        const f32x4 uu = *(const f32x4*)(u2v + rb * 16 + lgrp * 4);
#pragma unroll
        for (int cb = 0; cb < 4; ++cb) acc[rb][cb] += uu;
    }

    // ---- fragment-domain window dots + butterfly over lgrp ----
    float sKeep[9];
    float betaK = 0.f;
#pragma unroll
    for (int cb = 0; cb < 4; ++cb) {
        const int row = w * 4 + cb;
        float s[9];
        float sb = 0.f;
#pragma unroll
        for (int n = 0; n < 9; ++n) {
            const int hpx = (row + n / 3) * HX + (lcol + n % 3);
            float a = 0.f;
#pragma unroll
            for (int rb = 0; rb < 8; ++rb) {
                const int q = rb * 4 + lgrp;
                const uint2 d = *(const uint2*)(sH + hpx * 128 +
                                 (((q >> 1) ^ (hpx & 15)) * 8) + (q & 1) * 4);
                a += acc[rb][cb][0] * bflo(d.x) + acc[rb][cb][1] * bfhi(d.x)
                   + acc[rb][cb][2] * bflo(d.y) + acc[rb][cb][3] * bfhi(d.y);
                if (n == 4) {   // center: also beta partial = v2 . f_p
                    const f32x4 vv = *(const f32x4*)(v2v + rb * 16 + lgrp * 4);
                    sb += vv[0] * bflo(d.x) + vv[1] * bfhi(d.x)
                        + vv[2] * bflo(d.y) + vv[3] * bfhi(d.y);
                }
            }
            s[n] = a;
        }
#pragma unroll
        for (int n = 0; n < 9; ++n) {
            s[n] += __shfl_xor(s[n], 16, 64);
            s[n] += __shfl_xor(s[n], 32, 64);
        }
        sb += __shfl_xor(sb, 16, 64);
        sb += __shfl_xor(sb, 32, 64);
        if (lgrp == cb) {
#pragma unroll
            for (int n = 0; n < 9; ++n) sKeep[n] = s[n];
            betaK = sb;
        }
    }

    // ---- softmax + flow PV: lane <-> px (row = w*4+lgrp, col = lcol) ----
    const int y = y0 + w * 4 + lgrp;
    const int x = x0 + lcol;
    const float c0 = *c0p;
    const float scale = 0.08838834764831845f;   // 1/sqrt(128)

    float sv[9], mk[9];
    int spn[9];
    float m = -1e30f;
#pragma unroll
    for (int n = 0; n < 9; ++n) {
        const int yn = y + n / 3 - 1, xn = x + n % 3 - 1;
        const bool okn = (yn >= 0) && (yn < H_) && (xn >= 0) && (xn < W_);
        mk[n]  = okn ? 1.f : 0.f;
        spn[n] = okn ? yn * W_ + xn : y * W_ + x;
        sv[n]  = okn ? (sKeep[n] + betaK + c0) * scale : 0.f;
        m = fmaxf(m, sv[n]);
    }
    float e[9], sum = 0.f;
#pragma unroll
    for (int n = 0; n < 9; ++n) { e[n] = __expf(sv[n] - m); sum += e[n]; }
    const float inv = 1.f / sum;

    const float* f0 = flow + (size_t)b * 2 * HW_;
    float o0 = 0.f, o1 = 0.f;
#pragma unroll
    for (int n = 0; n < 9; ++n) {
        const float pr = e[n] * inv * mk[n];
        o0 += pr * f0[spn[n]];
        o1 += pr * f0[HW_ + spn[n]];
    }
    const int sp = y * W_ + x;
    out[(size_t)b * 2 * HW_ + sp]       = o0;
    out[(size_t)b * 2 * HW_ + HW_ + sp] = o1;
}

extern "C" void kernel_launch(void* const* d_in, const int* in_sizes, int n_in,
                              void* d_out, int out_size, void* d_ws, size_t ws_size,
                              hipStream_t stream) {
    const float* f   = (const float*)d_in[0];
    const float* flw = (const float*)d_in[1];
    const float* Wq  = (const float*)d_in[2];
    const float* bq  = (const float*)d_in[3];
    const float* Wk  = (const float*)d_in[4];
    const float* bk  = (const float*)d_in[5];
    float* out = (float*)d_out;

    float* Mc    = (float*)d_ws;                  // 64 KB
    short* Apack = (short*)(Mc + 128 * 128);      // 32 KB
    float* u2    = (float*)(Apack + 128 * 128);   // 512 B
    float* v2    = u2 + 128;                      // 512 B
    float* c0    = v2 + 128;                      // 4 B

    mc_kernel<<<128, 128, 0, stream>>>(Wq, Wk, Mc);
    pack_kernel<<<9, 256, 0, stream>>>(Mc, Wq, Wk, bq, bk, Apack, u2, v2, c0);
    fused_kernel<<<576, 128, 0, stream>>>(f, Apack, u2, v2, c0, flw, out);
}